// Round 2
// baseline (592.646 us; speedup 1.0000x reference)
//
#include <hip/hip_runtime.h>

// VectorQuantizer: z [16,4096,256] f32, embedding [1024,256] f32
// out (f32, flat): z_q[16777216] | vq_loss[1] | commitment_loss[1] | idxs-as-float[65536]

#define ROWS 65536
#define EDIM 256
#define NEMB 1024
#define OUT_VQ  16777216
#define OUT_CM  16777217
#define OUT_IDX 16777218
#define MARGIN  0.25f
#define FLAGBIT (1 << 30)

typedef __attribute__((ext_vector_type(8))) short bf16x8;
typedef __attribute__((ext_vector_type(4))) float f32x4;

__device__ inline unsigned short f2bf(float x) {
  unsigned u = __builtin_bit_cast(unsigned, x);
  unsigned r = (u + 0x7fff + ((u >> 16) & 1)) >> 16;
  return (unsigned short)r;
}
__device__ inline float bf2f(unsigned short h) {
  unsigned u = ((unsigned)h) << 16;
  return __builtin_bit_cast(float, u);
}

// ---------------- split z into bf16 hi/lo (stored in d_out z_q region) ----------------
__global__ __launch_bounds__(256) void zsplit_kernel(const float* __restrict__ z,
                                                     unsigned short* __restrict__ zhi,
                                                     unsigned short* __restrict__ zlo) {
  size_t gid = (size_t)blockIdx.x * 256 + threadIdx.x;   // 2,097,152 threads, 8 elems each
  const float4* z4 = (const float4*)z;
  float4 v0 = z4[gid * 2];
  float4 v1 = z4[gid * 2 + 1];
  unsigned short h0 = f2bf(v0.x), h1 = f2bf(v0.y), h2 = f2bf(v0.z), h3 = f2bf(v0.w);
  unsigned short h4 = f2bf(v1.x), h5 = f2bf(v1.y), h6 = f2bf(v1.z), h7 = f2bf(v1.w);
  unsigned short l0 = f2bf(v0.x - bf2f(h0)), l1 = f2bf(v0.y - bf2f(h1));
  unsigned short l2 = f2bf(v0.z - bf2f(h2)), l3 = f2bf(v0.w - bf2f(h3));
  unsigned short l4 = f2bf(v1.x - bf2f(h4)), l5 = f2bf(v1.y - bf2f(h5));
  unsigned short l6 = f2bf(v1.z - bf2f(h6)), l7 = f2bf(v1.w - bf2f(h7));
  uint4 ph, pl;
  ph.x = (unsigned)h0 | ((unsigned)h1 << 16); ph.y = (unsigned)h2 | ((unsigned)h3 << 16);
  ph.z = (unsigned)h4 | ((unsigned)h5 << 16); ph.w = (unsigned)h6 | ((unsigned)h7 << 16);
  pl.x = (unsigned)l0 | ((unsigned)l1 << 16); pl.y = (unsigned)l2 | ((unsigned)l3 << 16);
  pl.z = (unsigned)l4 | ((unsigned)l5 << 16); pl.w = (unsigned)l6 | ((unsigned)l7 << 16);
  ((uint4*)zhi)[gid] = ph;
  ((uint4*)zlo)[gid] = pl;
}

__global__ __launch_bounds__(256) void esplit_kernel(const float* __restrict__ emb,
                                                     unsigned short* __restrict__ ehi,
                                                     unsigned short* __restrict__ elo) {
  size_t gid = (size_t)blockIdx.x * 256 + threadIdx.x;   // 32768 threads, 8 elems each
  const float4* e4 = (const float4*)emb;
  float4 v0 = e4[gid * 2];
  float4 v1 = e4[gid * 2 + 1];
  unsigned short h0 = f2bf(v0.x), h1 = f2bf(v0.y), h2 = f2bf(v0.z), h3 = f2bf(v0.w);
  unsigned short h4 = f2bf(v1.x), h5 = f2bf(v1.y), h6 = f2bf(v1.z), h7 = f2bf(v1.w);
  unsigned short l0 = f2bf(v0.x - bf2f(h0)), l1 = f2bf(v0.y - bf2f(h1));
  unsigned short l2 = f2bf(v0.z - bf2f(h2)), l3 = f2bf(v0.w - bf2f(h3));
  unsigned short l4 = f2bf(v1.x - bf2f(h4)), l5 = f2bf(v1.y - bf2f(h5));
  unsigned short l6 = f2bf(v1.z - bf2f(h6)), l7 = f2bf(v1.w - bf2f(h7));
  uint4 ph, pl;
  ph.x = (unsigned)h0 | ((unsigned)h1 << 16); ph.y = (unsigned)h2 | ((unsigned)h3 << 16);
  ph.z = (unsigned)h4 | ((unsigned)h5 << 16); ph.w = (unsigned)h6 | ((unsigned)h7 << 16);
  pl.x = (unsigned)l0 | ((unsigned)l1 << 16); pl.y = (unsigned)l2 | ((unsigned)l3 << 16);
  pl.z = (unsigned)l4 | ((unsigned)l5 << 16); pl.w = (unsigned)l6 | ((unsigned)l7 << 16);
  ((uint4*)ehi)[gid] = ph;
  ((uint4*)elo)[gid] = pl;
}

// ---------------- e2: per-code squared norm (identical to round 1) ----------------
__global__ __launch_bounds__(256) void e2_kernel(const float* __restrict__ emb,
                                                 float* __restrict__ e2) {
  int c = blockIdx.x * 256 + threadIdx.x;
  const float4* p = (const float4*)(emb + (size_t)c * EDIM);
  float s = 0.f;
  #pragma unroll 8
  for (int j = 0; j < EDIM / 4; ++j) {
    float4 v = p[j];
    s += v.x * v.x; s += v.y * v.y; s += v.z * v.z; s += v.w * v.w;
  }
  e2[c] = s;
}

// ---------------- MFMA bf16-split argmax with top-2 margin tracking ----------------
// sim' = e2[c] - 2*dot (z^2 dropped: row-constant, cancels in argmax/gap)
__global__ __launch_bounds__(512, 4) void argmax_kernel(
    const unsigned short* __restrict__ zhi, const unsigned short* __restrict__ zlo,
    const unsigned short* __restrict__ ehi, const unsigned short* __restrict__ elo,
    const float* __restrict__ e2, int* __restrict__ idxs) {
  __shared__ short tiles[4][128 * 40];   // Ahi, Alo, Bhi, Blo; stride 40 shorts (80B, 2-way max)

  const int tid  = threadIdx.x;
  const int lane = tid & 63;
  const int w    = tid >> 6;
  const int wr   = w >> 1;        // 0..3: 32-row group
  const int wc   = w & 1;         // 0..1: 64-col group
  const int q    = lane >> 4;     // k-group
  const int lr   = lane & 15;
  const int row0 = blockIdx.x * 128;

  const int sr = tid >> 2;        // staging row 0..127
  const int sk = (tid & 3) * 8;   // staging k offset (bf16 units)

  float b1[8], b2[8]; int i1[8];
  #pragma unroll
  for (int s = 0; s < 8; ++s) { b1[s] = -3.4e38f; b2[s] = -3.4e38f; i1[s] = 0; }

  for (int ncI = 0; ncI < 8; ++ncI) {
    const int nc = ncI * 128;
    f32x4 acc[2][4];
    #pragma unroll
    for (int ms = 0; ms < 2; ++ms)
      #pragma unroll
      for (int ns = 0; ns < 4; ++ns)
        acc[ms][ns] = (f32x4){0.f, 0.f, 0.f, 0.f};

    for (int kb = 0; kb < 8; ++kb) {
      const int ko = kb * 32 + sk;
      __syncthreads();
      {
        uint4 a_h = *(const uint4*)&zhi[(size_t)(row0 + sr) * EDIM + ko];
        uint4 a_l = *(const uint4*)&zlo[(size_t)(row0 + sr) * EDIM + ko];
        uint4 b_h = *(const uint4*)&ehi[(size_t)(nc + sr) * EDIM + ko];
        uint4 b_l = *(const uint4*)&elo[(size_t)(nc + sr) * EDIM + ko];
        int off = sr * 40 + sk;
        *(uint4*)&tiles[0][off] = a_h;
        *(uint4*)&tiles[1][off] = a_l;
        *(uint4*)&tiles[2][off] = b_h;
        *(uint4*)&tiles[3][off] = b_l;
      }
      __syncthreads();
      bf16x8 ah[2], al[2];
      #pragma unroll
      for (int ms = 0; ms < 2; ++ms) {
        int off = (wr * 32 + ms * 16 + lr) * 40 + q * 8;
        ah[ms] = *(const bf16x8*)&tiles[0][off];
        al[ms] = *(const bf16x8*)&tiles[1][off];
      }
      #pragma unroll
      for (int nh = 0; nh < 2; ++nh) {
        bf16x8 bh[2], bl[2];
        #pragma unroll
        for (int j = 0; j < 2; ++j) {
          int off = (wc * 64 + (nh * 2 + j) * 16 + lr) * 40 + q * 8;
          bh[j] = *(const bf16x8*)&tiles[2][off];
          bl[j] = *(const bf16x8*)&tiles[3][off];
        }
        #pragma unroll
        for (int ms = 0; ms < 2; ++ms)
          #pragma unroll
          for (int j = 0; j < 2; ++j) {
            int ns = nh * 2 + j;
            acc[ms][ns] = __builtin_amdgcn_mfma_f32_16x16x32_bf16(ah[ms], bh[j], acc[ms][ns], 0, 0, 0);
            acc[ms][ns] = __builtin_amdgcn_mfma_f32_16x16x32_bf16(al[ms], bh[j], acc[ms][ns], 0, 0, 0);
            acc[ms][ns] = __builtin_amdgcn_mfma_f32_16x16x32_bf16(ah[ms], bl[j], acc[ms][ns], 0, 0, 0);
          }
      }
    }
    // epilogue: running top-2 per row-slot
    #pragma unroll
    for (int ns = 0; ns < 4; ++ns) {
      int c = nc + wc * 64 + ns * 16 + lr;
      float e2v = e2[c];
      #pragma unroll
      for (int ms = 0; ms < 2; ++ms)
        #pragma unroll
        for (int r = 0; r < 4; ++r) {
          float sim = fmaf(acc[ms][ns][r], -2.0f, e2v);
          int s = ms * 4 + r;
          bool gt = sim > b1[s];
          b2[s] = fmaxf(b2[s], gt ? b1[s] : sim);
          if (gt) { b1[s] = sim; i1[s] = c; }
        }
    }
  }

  // cross-lane reduce over the 16 col-lanes (masks 1,2,4,8), idx tie-break min
  #pragma unroll
  for (int mask = 1; mask <= 8; mask <<= 1) {
    #pragma unroll
    for (int s = 0; s < 8; ++s) {
      float ov1 = __shfl_xor(b1[s], mask);
      int   oi  = __shfl_xor(i1[s], mask);
      float ov2 = __shfl_xor(b2[s], mask);
      float nb2 = fmaxf(fmaxf(b2[s], ov2), fminf(b1[s], ov1));
      bool take = (ov1 > b1[s]) || (ov1 == b1[s] && oi < i1[s]);
      if (take) { b1[s] = ov1; i1[s] = oi; }
      b2[s] = nb2;
    }
  }

  __syncthreads();   // done with GEMM tiles; reuse LDS
  float* rv1 = (float*)&tiles[0][0];
  int*   ri1 = (int*)&tiles[1][0];
  float* rv2 = (float*)&tiles[2][0];
  if (wc == 0 && lr == 0) {
    #pragma unroll
    for (int s = 0; s < 8; ++s) {
      int R = wr * 32 + (s >> 2) * 16 + q * 4 + (s & 3);
      rv1[R] = b1[s]; ri1[R] = i1[s]; rv2[R] = b2[s];
    }
  }
  __syncthreads();
  if (wc == 1 && lr == 0) {
    #pragma unroll
    for (int s = 0; s < 8; ++s) {
      int R = wr * 32 + (s >> 2) * 16 + q * 4 + (s & 3);
      float av1 = rv1[R]; int ai = ri1[R]; float av2 = rv2[R];
      float m2 = fmaxf(fmaxf(av2, b2[s]), fminf(av1, b1[s]));
      bool take = (b1[s] > av1) || (b1[s] == av1 && i1[s] < ai);
      float m1 = take ? b1[s] : av1;
      int   mi = take ? i1[s] : ai;
      idxs[row0 + R] = mi | ((m1 - m2 < MARGIN) ? FLAGBIT : 0);
    }
  }
}

// ---------------- exact fp32 rescue for narrow-margin rows (replicates round-1 math) ----
__global__ __launch_bounds__(256) void rescue_kernel(const float* __restrict__ z,
                                                     const float* __restrict__ emb,
                                                     const float* __restrict__ e2,
                                                     int* __restrict__ idxs) {
  __shared__ float zrow[EDIM];
  __shared__ float z2s;
  __shared__ float rv[256];
  __shared__ int   ri[256];
  const int tid = threadIdx.x;
  const float4* z4 = (const float4*)z;

  for (int j = 0; j < 256; ++j) {
    int row = blockIdx.x * 256 + j;
    int idx = idxs[row];
    if (!(idx & FLAGBIT)) continue;     // block-uniform

    if (tid < 64) ((float4*)zrow)[tid] = z4[(size_t)row * 64 + tid];
    __syncthreads();
    if (tid == 0) {
      float s = 0.f;
      for (int k = 0; k < 64; ++k) {
        float4 v = ((float4*)zrow)[k];
        s += v.x * v.x; s += v.y * v.y; s += v.z * v.z; s += v.w * v.w;
      }
      z2s = s;
    }
    __syncthreads();

    float bv = -3.4e38f; int bi = 0;
    #pragma unroll
    for (int cc = 0; cc < 4; ++cc) {
      int c = cc * 256 + tid;
      const float4* e4 = (const float4*)(emb + (size_t)c * EDIM);
      float dot = 0.f;
      for (int k = 0; k < 64; ++k) {
        float4 a = ((float4*)zrow)[k];
        float4 b = e4[k];
        dot = fmaf(a.x, b.x, dot);
        dot = fmaf(a.y, b.y, dot);
        dot = fmaf(a.z, b.z, dot);
        dot = fmaf(a.w, b.w, dot);
      }
      float t = z2s + e2[c];
      float s = fmaf(dot, -2.0f, t);
      if (s > bv || (s == bv && c < bi)) { bv = s; bi = c; }
    }
    rv[tid] = bv; ri[tid] = bi;
    __syncthreads();
    for (int sN = 128; sN > 0; sN >>= 1) {
      if (tid < sN) {
        float ov = rv[tid + sN]; int oi = ri[tid + sN];
        if (ov > rv[tid] || (ov == rv[tid] && oi < ri[tid])) { rv[tid] = ov; ri[tid] = oi; }
      }
      __syncthreads();
    }
    if (tid == 0) idxs[row] = ri[0];
    __syncthreads();
  }
}

// ---------------- gather z_q + squared-diff partial sums + idxf ----------------
__global__ __launch_bounds__(256) void gather_kernel(
    const float* __restrict__ z, const float* __restrict__ emb,
    const int* __restrict__ idxs, float* __restrict__ out,
    float* __restrict__ partials, float* __restrict__ idxf) {
  const int tid = threadIdx.x;
  const int b = blockIdx.x;            // 1024 blocks, 64 rows each
  const float4* z4 = (const float4*)z;
  float4* q4 = (float4*)out;

  if (tid < 64) {
    int r2 = b * 64 + tid;
    idxf[r2] = (float)(idxs[r2] & 1023);
  }

  float acc = 0.f;
  #pragma unroll
  for (int i = 0; i < 16; ++i) {
    int f = b * 4096 + tid + 256 * i;  // float4 index
    int row = f >> 6;
    int c4 = f & 63;
    int e = idxs[row] & 1023;
    float4 ev = *(const float4*)&emb[(size_t)e * EDIM + 4 * c4];
    float4 zv = z4[f];
    q4[f] = ev;
    float dx = ev.x - zv.x, dy = ev.y - zv.y, dz = ev.z - zv.z, dw = ev.w - zv.w;
    acc += dx * dx + dy * dy + dz * dz + dw * dw;
  }
  __shared__ float red[256];
  red[tid] = acc;
  __syncthreads();
  #pragma unroll
  for (int sN = 128; sN > 0; sN >>= 1) {
    if (tid < sN) red[tid] += red[tid + sN];
    __syncthreads();
  }
  if (tid == 0) partials[b] = red[0];
}

__global__ void finalize_kernel(const float* __restrict__ partials,
                                float* __restrict__ out) {
  if (threadIdx.x == 0 && blockIdx.x == 0) {
    double s = 0.0;
    for (int i = 0; i < 1024; ++i) s += (double)partials[i];
    float m = (float)(s / 16777216.0);
    out[OUT_VQ] = m;
    out[OUT_CM] = 0.25f * m;
  }
}

extern "C" void kernel_launch(void* const* d_in, const int* in_sizes, int n_in,
                              void* d_out, int out_size, void* d_ws, size_t ws_size,
                              hipStream_t stream) {
  const float* z   = (const float*)d_in[0];
  const float* emb = (const float*)d_in[1];
  float* out = (float*)d_out;

  // z_q region doubles as bf16 hi/lo staging (64MB = 32MB hi + 32MB lo), overwritten by gather
  unsigned short* zhi = (unsigned short*)d_out;
  unsigned short* zlo = zhi + 16777216;

  // ws: ehi 512KB | elo 512KB | e2 4KB | idxs 256KB | partials 4KB  (~1.3MB)
  unsigned short* ehi = (unsigned short*)d_ws;
  unsigned short* elo = ehi + 262144;
  float* e2       = (float*)(elo + 262144);
  int*   idxs     = (int*)(e2 + 1024);
  float* partials = (float*)(idxs + 65536);

  zsplit_kernel<<<8192, 256, 0, stream>>>(z, zhi, zlo);
  esplit_kernel<<<128, 256, 0, stream>>>(emb, ehi, elo);
  e2_kernel<<<NEMB / 256, 256, 0, stream>>>(emb, e2);
  argmax_kernel<<<ROWS / 128, 512, 0, stream>>>(zhi, zlo, ehi, elo, e2, idxs);
  rescue_kernel<<<256, 256, 0, stream>>>(z, emb, e2, idxs);
  gather_kernel<<<1024, 256, 0, stream>>>(z, emb, idxs, out, partials, out + OUT_IDX);
  finalize_kernel<<<1, 64, 0, stream>>>(partials, out);
}

// Round 3
// 361.976 us; speedup vs baseline: 1.6373x; 1.6373x over previous
//
#include <hip/hip_runtime.h>

// VectorQuantizer: z [16,4096,256] f32, embedding [1024,256] f32
// out (f32, flat): z_q[16777216] | vq_loss[1] | commitment_loss[1] | idxs-as-float[65536]

#define ROWS 65536
#define EDIM 256
#define NEMB 1024
#define OUT_VQ  16777216
#define OUT_CM  16777217
#define OUT_IDX 16777218
#define MARGIN  0.25f

typedef __attribute__((ext_vector_type(8))) short bf16x8;
typedef __attribute__((ext_vector_type(4))) float f32x4;

__device__ inline unsigned short f2bf(float x) {
  unsigned u = __builtin_bit_cast(unsigned, x);
  unsigned r = (u + 0x7fff + ((u >> 16) & 1)) >> 16;
  return (unsigned short)r;
}
__device__ inline float bf2f(unsigned short h) {
  unsigned u = ((unsigned)h) << 16;
  return __builtin_bit_cast(float, u);
}

__global__ void init_kernel(int* __restrict__ cnt) {
  if (threadIdx.x == 0 && blockIdx.x == 0) cnt[0] = 0;
}

// ---------------- split z into bf16 hi/lo (stored in d_out z_q region) ----------------
__global__ __launch_bounds__(256) void zsplit_kernel(const float* __restrict__ z,
                                                     unsigned short* __restrict__ zhi,
                                                     unsigned short* __restrict__ zlo) {
  size_t gid = (size_t)blockIdx.x * 256 + threadIdx.x;   // 2,097,152 threads, 8 elems each
  const float4* z4 = (const float4*)z;
  float4 v0 = z4[gid * 2];
  float4 v1 = z4[gid * 2 + 1];
  unsigned short h0 = f2bf(v0.x), h1 = f2bf(v0.y), h2 = f2bf(v0.z), h3 = f2bf(v0.w);
  unsigned short h4 = f2bf(v1.x), h5 = f2bf(v1.y), h6 = f2bf(v1.z), h7 = f2bf(v1.w);
  unsigned short l0 = f2bf(v0.x - bf2f(h0)), l1 = f2bf(v0.y - bf2f(h1));
  unsigned short l2 = f2bf(v0.z - bf2f(h2)), l3 = f2bf(v0.w - bf2f(h3));
  unsigned short l4 = f2bf(v1.x - bf2f(h4)), l5 = f2bf(v1.y - bf2f(h5));
  unsigned short l6 = f2bf(v1.z - bf2f(h6)), l7 = f2bf(v1.w - bf2f(h7));
  uint4 ph, pl;
  ph.x = (unsigned)h0 | ((unsigned)h1 << 16); ph.y = (unsigned)h2 | ((unsigned)h3 << 16);
  ph.z = (unsigned)h4 | ((unsigned)h5 << 16); ph.w = (unsigned)h6 | ((unsigned)h7 << 16);
  pl.x = (unsigned)l0 | ((unsigned)l1 << 16); pl.y = (unsigned)l2 | ((unsigned)l3 << 16);
  pl.z = (unsigned)l4 | ((unsigned)l5 << 16); pl.w = (unsigned)l6 | ((unsigned)l7 << 16);
  ((uint4*)zhi)[gid] = ph;
  ((uint4*)zlo)[gid] = pl;
}

__global__ __launch_bounds__(256) void esplit_kernel(const float* __restrict__ emb,
                                                     unsigned short* __restrict__ ehi,
                                                     unsigned short* __restrict__ elo,
                                                     float* __restrict__ e2) {
  size_t gid = (size_t)blockIdx.x * 256 + threadIdx.x;   // 32768 threads, 8 elems each
  const float4* e4 = (const float4*)emb;
  float4 v0 = e4[gid * 2];
  float4 v1 = e4[gid * 2 + 1];
  unsigned short h0 = f2bf(v0.x), h1 = f2bf(v0.y), h2 = f2bf(v0.z), h3 = f2bf(v0.w);
  unsigned short h4 = f2bf(v1.x), h5 = f2bf(v1.y), h6 = f2bf(v1.z), h7 = f2bf(v1.w);
  unsigned short l0 = f2bf(v0.x - bf2f(h0)), l1 = f2bf(v0.y - bf2f(h1));
  unsigned short l2 = f2bf(v0.z - bf2f(h2)), l3 = f2bf(v0.w - bf2f(h3));
  unsigned short l4 = f2bf(v1.x - bf2f(h4)), l5 = f2bf(v1.y - bf2f(h5));
  unsigned short l6 = f2bf(v1.z - bf2f(h6)), l7 = f2bf(v1.w - bf2f(h7));
  uint4 ph, pl;
  ph.x = (unsigned)h0 | ((unsigned)h1 << 16); ph.y = (unsigned)h2 | ((unsigned)h3 << 16);
  ph.z = (unsigned)h4 | ((unsigned)h5 << 16); ph.w = (unsigned)h6 | ((unsigned)h7 << 16);
  pl.x = (unsigned)l0 | ((unsigned)l1 << 16); pl.y = (unsigned)l2 | ((unsigned)l3 << 16);
  pl.z = (unsigned)l4 | ((unsigned)l5 << 16); pl.w = (unsigned)l6 | ((unsigned)l7 << 16);
  ((uint4*)ehi)[gid] = ph;
  ((uint4*)elo)[gid] = pl;
}

// ---------------- e2: per-code squared norm (identical rounding to round 1) ----------------
__global__ __launch_bounds__(256) void e2_kernel(const float* __restrict__ emb,
                                                 float* __restrict__ e2) {
  int c = blockIdx.x * 256 + threadIdx.x;
  const float4* p = (const float4*)(emb + (size_t)c * EDIM);
  float s = 0.f;
  #pragma unroll 8
  for (int j = 0; j < EDIM / 4; ++j) {
    float4 v = p[j];
    s += v.x * v.x; s += v.y * v.y; s += v.z * v.z; s += v.w * v.w;
  }
  e2[c] = s;
}

// ---------------- MFMA bf16-split argmax with top-2 margin tracking ----------------
// sim' = e2[c] - 2*dot (z^2 dropped: row-constant, cancels in argmax/gap)
__global__ __launch_bounds__(512, 4) void argmax_kernel(
    const unsigned short* __restrict__ zhi, const unsigned short* __restrict__ zlo,
    const unsigned short* __restrict__ ehi, const unsigned short* __restrict__ elo,
    const float* __restrict__ e2, int* __restrict__ idxs,
    int* __restrict__ cnt, int* __restrict__ worklist) {
  __shared__ short tiles[4][128 * 40];   // Ahi, Alo, Bhi, Blo; stride 40 shorts (80B, 2-way max)

  const int tid  = threadIdx.x;
  const int lane = tid & 63;
  const int w    = tid >> 6;
  const int wr   = w >> 1;        // 0..3: 32-row group
  const int wc   = w & 1;         // 0..1: 64-col group
  const int q    = lane >> 4;     // k-group
  const int lr   = lane & 15;
  const int row0 = blockIdx.x * 128;

  const int sr = tid >> 2;        // staging row 0..127
  const int sk = (tid & 3) * 8;   // staging k offset (bf16 units)

  float b1[8], b2[8]; int i1[8];
  #pragma unroll
  for (int s = 0; s < 8; ++s) { b1[s] = -3.4e38f; b2[s] = -3.4e38f; i1[s] = 0; }

  for (int ncI = 0; ncI < 8; ++ncI) {
    const int nc = ncI * 128;
    f32x4 acc[2][4];
    #pragma unroll
    for (int ms = 0; ms < 2; ++ms)
      #pragma unroll
      for (int ns = 0; ns < 4; ++ns)
        acc[ms][ns] = (f32x4){0.f, 0.f, 0.f, 0.f};

    for (int kb = 0; kb < 8; ++kb) {
      const int ko = kb * 32 + sk;
      __syncthreads();
      {
        uint4 a_h = *(const uint4*)&zhi[(size_t)(row0 + sr) * EDIM + ko];
        uint4 a_l = *(const uint4*)&zlo[(size_t)(row0 + sr) * EDIM + ko];
        uint4 b_h = *(const uint4*)&ehi[(size_t)(nc + sr) * EDIM + ko];
        uint4 b_l = *(const uint4*)&elo[(size_t)(nc + sr) * EDIM + ko];
        int off = sr * 40 + sk;
        *(uint4*)&tiles[0][off] = a_h;
        *(uint4*)&tiles[1][off] = a_l;
        *(uint4*)&tiles[2][off] = b_h;
        *(uint4*)&tiles[3][off] = b_l;
      }
      __syncthreads();
      bf16x8 ah[2], al[2];
      #pragma unroll
      for (int ms = 0; ms < 2; ++ms) {
        int off = (wr * 32 + ms * 16 + lr) * 40 + q * 8;
        ah[ms] = *(const bf16x8*)&tiles[0][off];
        al[ms] = *(const bf16x8*)&tiles[1][off];
      }
      #pragma unroll
      for (int nh = 0; nh < 2; ++nh) {
        bf16x8 bh[2], bl[2];
        #pragma unroll
        for (int j = 0; j < 2; ++j) {
          int off = (wc * 64 + (nh * 2 + j) * 16 + lr) * 40 + q * 8;
          bh[j] = *(const bf16x8*)&tiles[2][off];
          bl[j] = *(const bf16x8*)&tiles[3][off];
        }
        #pragma unroll
        for (int ms = 0; ms < 2; ++ms)
          #pragma unroll
          for (int j = 0; j < 2; ++j) {
            int ns = nh * 2 + j;
            acc[ms][ns] = __builtin_amdgcn_mfma_f32_16x16x32_bf16(ah[ms], bh[j], acc[ms][ns], 0, 0, 0);
            acc[ms][ns] = __builtin_amdgcn_mfma_f32_16x16x32_bf16(al[ms], bh[j], acc[ms][ns], 0, 0, 0);
            acc[ms][ns] = __builtin_amdgcn_mfma_f32_16x16x32_bf16(ah[ms], bl[j], acc[ms][ns], 0, 0, 0);
          }
      }
    }
    // epilogue: running top-2 per row-slot
    #pragma unroll
    for (int ns = 0; ns < 4; ++ns) {
      int c = nc + wc * 64 + ns * 16 + lr;
      float e2v = e2[c];
      #pragma unroll
      for (int ms = 0; ms < 2; ++ms)
        #pragma unroll
        for (int r = 0; r < 4; ++r) {
          float sim = fmaf(acc[ms][ns][r], -2.0f, e2v);
          int s = ms * 4 + r;
          bool gt = sim > b1[s];
          b2[s] = fmaxf(b2[s], gt ? b1[s] : sim);
          if (gt) { b1[s] = sim; i1[s] = c; }
        }
    }
  }

  // cross-lane reduce over the 16 col-lanes (masks 1,2,4,8), idx tie-break min
  #pragma unroll
  for (int mask = 1; mask <= 8; mask <<= 1) {
    #pragma unroll
    for (int s = 0; s < 8; ++s) {
      float ov1 = __shfl_xor(b1[s], mask);
      int   oi  = __shfl_xor(i1[s], mask);
      float ov2 = __shfl_xor(b2[s], mask);
      float nb2 = fmaxf(fmaxf(b2[s], ov2), fminf(b1[s], ov1));
      bool take = (ov1 > b1[s]) || (ov1 == b1[s] && oi < i1[s]);
      if (take) { b1[s] = ov1; i1[s] = oi; }
      b2[s] = nb2;
    }
  }

  __syncthreads();   // done with GEMM tiles; reuse LDS
  float* rv1 = (float*)&tiles[0][0];
  int*   ri1 = (int*)&tiles[1][0];
  float* rv2 = (float*)&tiles[2][0];
  if (wc == 0 && lr == 0) {
    #pragma unroll
    for (int s = 0; s < 8; ++s) {
      int R = wr * 32 + (s >> 2) * 16 + q * 4 + (s & 3);
      rv1[R] = b1[s]; ri1[R] = i1[s]; rv2[R] = b2[s];
    }
  }
  __syncthreads();
  if (wc == 1 && lr == 0) {
    #pragma unroll
    for (int s = 0; s < 8; ++s) {
      int R = wr * 32 + (s >> 2) * 16 + q * 4 + (s & 3);
      float av1 = rv1[R]; int ai = ri1[R]; float av2 = rv2[R];
      float m2 = fmaxf(fmaxf(av2, b2[s]), fminf(av1, b1[s]));
      bool take = (b1[s] > av1) || (b1[s] == av1 && i1[s] < ai);
      float m1 = take ? b1[s] : av1;
      int   mi = take ? i1[s] : ai;
      idxs[row0 + R] = mi;
      if (m1 - m2 < MARGIN) {
        int p = atomicAdd(cnt, 1);
        worklist[p] = row0 + R;
      }
    }
  }
}

// ---------------- exact fp32 rescue, grid-stride over compacted worklist ----------------
__global__ __launch_bounds__(256) void rescue_kernel(const float* __restrict__ z,
                                                     const float* __restrict__ emb,
                                                     const float* __restrict__ e2,
                                                     int* __restrict__ idxs,
                                                     const int* __restrict__ cnt,
                                                     const int* __restrict__ worklist) {
  __shared__ float zrow[EDIM];
  __shared__ float z2s;
  __shared__ float rv[256];
  __shared__ int   ri[256];
  const int tid = threadIdx.x;
  const float4* z4 = (const float4*)z;
  const int n = cnt[0];

  for (int wi = blockIdx.x; wi < n; wi += gridDim.x) {
    int row = worklist[wi];

    if (tid < 64) ((float4*)zrow)[tid] = z4[(size_t)row * 64 + tid];
    __syncthreads();
    if (tid == 0) {
      float s = 0.f;
      for (int k = 0; k < 64; ++k) {
        float4 v = ((float4*)zrow)[k];
        s += v.x * v.x; s += v.y * v.y; s += v.z * v.z; s += v.w * v.w;
      }
      z2s = s;
    }
    __syncthreads();

    float bv = -3.4e38f; int bi = 0;
    #pragma unroll
    for (int cc = 0; cc < 4; ++cc) {
      int c = cc * 256 + tid;
      const float4* e4 = (const float4*)(emb + (size_t)c * EDIM);
      float dot = 0.f;
      for (int k = 0; k < 64; ++k) {
        float4 a = ((float4*)zrow)[k];
        float4 b = e4[k];
        dot = fmaf(a.x, b.x, dot);
        dot = fmaf(a.y, b.y, dot);
        dot = fmaf(a.z, b.z, dot);
        dot = fmaf(a.w, b.w, dot);
      }
      float t = z2s + e2[c];
      float s = fmaf(dot, -2.0f, t);
      if (s > bv || (s == bv && c < bi)) { bv = s; bi = c; }
    }
    rv[tid] = bv; ri[tid] = bi;
    __syncthreads();
    for (int sN = 128; sN > 0; sN >>= 1) {
      if (tid < sN) {
        float ov = rv[tid + sN]; int oi = ri[tid + sN];
        if (ov > rv[tid] || (ov == rv[tid] && oi < ri[tid])) { rv[tid] = ov; ri[tid] = oi; }
      }
      __syncthreads();
    }
    if (tid == 0) idxs[row] = ri[0];
    __syncthreads();
  }
}

// ---------------- gather z_q + squared-diff partial sums + idxf ----------------
__global__ __launch_bounds__(256) void gather_kernel(
    const float* __restrict__ z, const float* __restrict__ emb,
    const int* __restrict__ idxs, float* __restrict__ out,
    float* __restrict__ partials, float* __restrict__ idxf) {
  const int tid = threadIdx.x;
  const int b = blockIdx.x;            // 1024 blocks, 64 rows each
  const float4* z4 = (const float4*)z;
  float4* q4 = (float4*)out;

  if (tid < 64) {
    int r2 = b * 64 + tid;
    idxf[r2] = (float)idxs[r2];
  }

  float acc = 0.f;
  #pragma unroll
  for (int i = 0; i < 16; ++i) {
    int f = b * 4096 + tid + 256 * i;  // float4 index
    int row = f >> 6;
    int c4 = f & 63;
    int e = idxs[row];
    float4 ev = *(const float4*)&emb[(size_t)e * EDIM + 4 * c4];
    float4 zv = z4[f];
    q4[f] = ev;
    float dx = ev.x - zv.x, dy = ev.y - zv.y, dz = ev.z - zv.z, dw = ev.w - zv.w;
    acc += dx * dx + dy * dy + dz * dz + dw * dw;
  }
  __shared__ float red[256];
  red[tid] = acc;
  __syncthreads();
  #pragma unroll
  for (int sN = 128; sN > 0; sN >>= 1) {
    if (tid < sN) red[tid] += red[tid + sN];
    __syncthreads();
  }
  if (tid == 0) partials[b] = red[0];
}

__global__ void finalize_kernel(const float* __restrict__ partials,
                                float* __restrict__ out) {
  if (threadIdx.x == 0 && blockIdx.x == 0) {
    double s = 0.0;
    for (int i = 0; i < 1024; ++i) s += (double)partials[i];
    float m = (float)(s / 16777216.0);
    out[OUT_VQ] = m;
    out[OUT_CM] = 0.25f * m;
  }
}

extern "C" void kernel_launch(void* const* d_in, const int* in_sizes, int n_in,
                              void* d_out, int out_size, void* d_ws, size_t ws_size,
                              hipStream_t stream) {
  const float* z   = (const float*)d_in[0];
  const float* emb = (const float*)d_in[1];
  float* out = (float*)d_out;

  // z_q region doubles as bf16 hi/lo staging (64MB = 32MB hi + 32MB lo), overwritten by gather
  unsigned short* zhi = (unsigned short*)d_out;
  unsigned short* zlo = zhi + 16777216;

  // ws: ehi 512KB | elo 512KB | e2 4KB | idxs 256KB | partials 4KB | cnt 16B | worklist 256KB
  unsigned short* ehi = (unsigned short*)d_ws;
  unsigned short* elo = ehi + 262144;
  float* e2       = (float*)(elo + 262144);
  int*   idxs     = (int*)(e2 + 1024);
  float* partials = (float*)(idxs + 65536);
  int*   cnt      = (int*)(partials + 1024);
  int*   worklist = cnt + 4;

  init_kernel<<<1, 64, 0, stream>>>(cnt);
  zsplit_kernel<<<8192, 256, 0, stream>>>(z, zhi, zlo);
  esplit_kernel<<<128, 256, 0, stream>>>(emb, ehi, elo, e2);
  e2_kernel<<<NEMB / 256, 256, 0, stream>>>(emb, e2);
  argmax_kernel<<<ROWS / 128, 512, 0, stream>>>(zhi, zlo, ehi, elo, e2, idxs, cnt, worklist);
  rescue_kernel<<<1024, 256, 0, stream>>>(z, emb, e2, idxs, cnt, worklist);
  gather_kernel<<<1024, 256, 0, stream>>>(z, emb, idxs, out, partials, out + OUT_IDX);
  finalize_kernel<<<1, 64, 0, stream>>>(partials, out);
}

// Round 4
// 268.356 us; speedup vs baseline: 2.2084x; 1.3489x over previous
//
#include <hip/hip_runtime.h>

// VectorQuantizer: z [16,4096,256] f32, embedding [1024,256] f32
// out (f32, flat): z_q[16777216] | vq_loss[1] | commitment_loss[1] | idxs-as-float[65536]

#define ROWS 65536
#define EDIM 256
#define NEMB 1024
#define OUT_VQ  16777216
#define OUT_CM  16777217
#define OUT_IDX 16777218
#define MARGIN  0.25f
#define RB 8

typedef __attribute__((ext_vector_type(8))) short bf16x8;
typedef __attribute__((ext_vector_type(4))) float f32x4;

__device__ inline unsigned short f2bf(float x) {
  unsigned u = __builtin_bit_cast(unsigned, x);
  unsigned r = (u + 0x7fff + ((u >> 16) & 1)) >> 16;
  return (unsigned short)r;
}
__device__ inline float bf2f(unsigned short h) {
  unsigned u = ((unsigned)h) << 16;
  return __builtin_bit_cast(float, u);
}
__device__ inline void gload_lds16(const void* g, void* l) {
  __builtin_amdgcn_global_load_lds((const __attribute__((address_space(1))) unsigned int*)g,
                                   (__attribute__((address_space(3))) unsigned int*)l,
                                   16, 0, 0);
}

// ---------------- split z into bf16 hi/lo (stored in d_out z_q region) ----------------
__global__ __launch_bounds__(256) void zsplit_kernel(const float* __restrict__ z,
                                                     unsigned short* __restrict__ zhi,
                                                     unsigned short* __restrict__ zlo) {
  size_t gid = (size_t)blockIdx.x * 256 + threadIdx.x;   // 2,097,152 threads, 8 elems each
  const float4* z4 = (const float4*)z;
  float4 v0 = z4[gid * 2];
  float4 v1 = z4[gid * 2 + 1];
  unsigned short h0 = f2bf(v0.x), h1 = f2bf(v0.y), h2 = f2bf(v0.z), h3 = f2bf(v0.w);
  unsigned short h4 = f2bf(v1.x), h5 = f2bf(v1.y), h6 = f2bf(v1.z), h7 = f2bf(v1.w);
  unsigned short l0 = f2bf(v0.x - bf2f(h0)), l1 = f2bf(v0.y - bf2f(h1));
  unsigned short l2 = f2bf(v0.z - bf2f(h2)), l3 = f2bf(v0.w - bf2f(h3));
  unsigned short l4 = f2bf(v1.x - bf2f(h4)), l5 = f2bf(v1.y - bf2f(h5));
  unsigned short l6 = f2bf(v1.z - bf2f(h6)), l7 = f2bf(v1.w - bf2f(h7));
  uint4 ph, pl;
  ph.x = (unsigned)h0 | ((unsigned)h1 << 16); ph.y = (unsigned)h2 | ((unsigned)h3 << 16);
  ph.z = (unsigned)h4 | ((unsigned)h5 << 16); ph.w = (unsigned)h6 | ((unsigned)h7 << 16);
  pl.x = (unsigned)l0 | ((unsigned)l1 << 16); pl.y = (unsigned)l2 | ((unsigned)l3 << 16);
  pl.z = (unsigned)l4 | ((unsigned)l5 << 16); pl.w = (unsigned)l6 | ((unsigned)l7 << 16);
  ((uint4*)zhi)[gid] = ph;
  ((uint4*)zlo)[gid] = pl;
}

__global__ __launch_bounds__(256) void esplit_kernel(const float* __restrict__ emb,
                                                     unsigned short* __restrict__ ehi,
                                                     unsigned short* __restrict__ elo) {
  size_t gid = (size_t)blockIdx.x * 256 + threadIdx.x;   // 32768 threads, 8 elems each
  const float4* e4 = (const float4*)emb;
  float4 v0 = e4[gid * 2];
  float4 v1 = e4[gid * 2 + 1];
  unsigned short h0 = f2bf(v0.x), h1 = f2bf(v0.y), h2 = f2bf(v0.z), h3 = f2bf(v0.w);
  unsigned short h4 = f2bf(v1.x), h5 = f2bf(v1.y), h6 = f2bf(v1.z), h7 = f2bf(v1.w);
  unsigned short l0 = f2bf(v0.x - bf2f(h0)), l1 = f2bf(v0.y - bf2f(h1));
  unsigned short l2 = f2bf(v0.z - bf2f(h2)), l3 = f2bf(v0.w - bf2f(h3));
  unsigned short l4 = f2bf(v1.x - bf2f(h4)), l5 = f2bf(v1.y - bf2f(h5));
  unsigned short l6 = f2bf(v1.z - bf2f(h6)), l7 = f2bf(v1.w - bf2f(h7));
  uint4 ph, pl;
  ph.x = (unsigned)h0 | ((unsigned)h1 << 16); ph.y = (unsigned)h2 | ((unsigned)h3 << 16);
  ph.z = (unsigned)h4 | ((unsigned)h5 << 16); ph.w = (unsigned)h6 | ((unsigned)h7 << 16);
  pl.x = (unsigned)l0 | ((unsigned)l1 << 16); pl.y = (unsigned)l2 | ((unsigned)l3 << 16);
  pl.z = (unsigned)l4 | ((unsigned)l5 << 16); pl.w = (unsigned)l6 | ((unsigned)l7 << 16);
  ((uint4*)ehi)[gid] = ph;
  ((uint4*)elo)[gid] = pl;
}

// ---------------- e2 + cnt reset ----------------
__global__ __launch_bounds__(256) void e2_kernel(const float* __restrict__ emb,
                                                 float* __restrict__ e2,
                                                 int* __restrict__ cnt) {
  if (blockIdx.x == 0 && threadIdx.x == 0) cnt[0] = 0;
  int c = blockIdx.x * 256 + threadIdx.x;
  const float4* p = (const float4*)(emb + (size_t)c * EDIM);
  float s = 0.f;
  #pragma unroll 8
  for (int j = 0; j < EDIM / 4; ++j) {
    float4 v = p[j];
    s += v.x * v.x; s += v.y * v.y; s += v.z * v.z; s += v.w * v.w;
  }
  e2[c] = s;
}

// ---------------- MFMA bf16-split argmax, global_load_lds + XOR swizzle ----------------
// LDS tile row-major [128][64] shorts (128B row = 8 x 16B slots).
// Source pre-swizzle: lane (r̂=lane>>3, s=lane&7) fetches global quad s^r̂ -> LDS slot s.
// Read applies same XOR: quad qq of row r lives at slot qq^(r&7).  (involution, rule 21)
__global__ __launch_bounds__(512, 4) void argmax_kernel(
    const unsigned short* __restrict__ zhi, const unsigned short* __restrict__ zlo,
    const unsigned short* __restrict__ ehi, const unsigned short* __restrict__ elo,
    const float* __restrict__ e2, int* __restrict__ idxs,
    int* __restrict__ cnt, int* __restrict__ worklist) {
  __shared__ short tiles[4][128 * 64];   // Ahi, Alo, Bhi, Blo = 64 KB

  const int tid  = threadIdx.x;
  const int w    = tid >> 6;      // wave 0..7
  const int lane = tid & 63;
  const int wr   = w >> 1;        // 0..3: 32-row group (MFMA mapping)
  const int wc   = w & 1;         // 0..1: 64-col group
  const int q    = lane >> 4;     // k-group
  const int lr   = lane & 15;
  const int row0 = blockIdx.x * 128;

  // staging mapping: wave -> (tile, half)
  const int st   = w >> 1;        // tile 0..3
  const int sh   = w & 1;         // half 0..1 (64 rows)
  const int lrow8 = lane >> 3;    // 0..7
  const int sq    = (lane & 7) ^ lrow8;   // pre-swizzled source quad

  const int xr = lr & 7;          // r&7 for all this lane's fragment rows

  float b1[8], b2[8]; int i1[8];
  #pragma unroll
  for (int s = 0; s < 8; ++s) { b1[s] = -3.4e38f; b2[s] = -3.4e38f; i1[s] = 0; }

  for (int ncI = 0; ncI < 8; ++ncI) {
    const int nc = ncI * 128;
    const unsigned short* gsrc =
        (st == 0) ? zhi + (size_t)row0 * EDIM :
        (st == 1) ? zlo + (size_t)row0 * EDIM :
        (st == 2) ? ehi + (size_t)nc * EDIM :
                    elo + (size_t)nc * EDIM;

    f32x4 acc[2][4];
    #pragma unroll
    for (int ms = 0; ms < 2; ++ms)
      #pragma unroll
      for (int ns = 0; ns < 4; ++ns)
        acc[ms][ns] = (f32x4){0.f, 0.f, 0.f, 0.f};

    for (int kb = 0; kb < 4; ++kb) {
      const int ko = kb * 64;
      __syncthreads();   // previous iteration's ds_reads drained
      #pragma unroll
      for (int j = 0; j < 8; ++j) {
        const int rbase = sh * 64 + j * 8;
        const unsigned short* g = gsrc + (size_t)(rbase + lrow8) * EDIM + ko + (sq << 3);
        gload_lds16(g, &tiles[st][rbase * 64]);
      }
      __syncthreads();   // vmcnt(0) drained by compiler before barrier

      #pragma unroll
      for (int ks = 0; ks < 2; ++ks) {
        const int so = (((ks << 2) + q) ^ xr) << 3;   // swizzled 16B slot, in shorts
        bf16x8 ah[2], al[2];
        #pragma unroll
        for (int ms = 0; ms < 2; ++ms) {
          int off = (wr * 32 + ms * 16 + lr) * 64 + so;
          ah[ms] = *(const bf16x8*)&tiles[0][off];
          al[ms] = *(const bf16x8*)&tiles[1][off];
        }
        #pragma unroll
        for (int nh = 0; nh < 2; ++nh) {
          bf16x8 bh[2], bl[2];
          #pragma unroll
          for (int j = 0; j < 2; ++j) {
            int off = (wc * 64 + (nh * 2 + j) * 16 + lr) * 64 + so;
            bh[j] = *(const bf16x8*)&tiles[2][off];
            bl[j] = *(const bf16x8*)&tiles[3][off];
          }
          #pragma unroll
          for (int ms = 0; ms < 2; ++ms)
            #pragma unroll
            for (int j = 0; j < 2; ++j) {
              int ns = nh * 2 + j;
              acc[ms][ns] = __builtin_amdgcn_mfma_f32_16x16x32_bf16(ah[ms], bh[j], acc[ms][ns], 0, 0, 0);
              acc[ms][ns] = __builtin_amdgcn_mfma_f32_16x16x32_bf16(al[ms], bh[j], acc[ms][ns], 0, 0, 0);
              acc[ms][ns] = __builtin_amdgcn_mfma_f32_16x16x32_bf16(ah[ms], bl[j], acc[ms][ns], 0, 0, 0);
            }
        }
      }
    }
    // epilogue: running top-2 per row-slot
    #pragma unroll
    for (int ns = 0; ns < 4; ++ns) {
      int c = nc + wc * 64 + ns * 16 + lr;
      float e2v = e2[c];
      #pragma unroll
      for (int ms = 0; ms < 2; ++ms)
        #pragma unroll
        for (int r = 0; r < 4; ++r) {
          float sim = fmaf(acc[ms][ns][r], -2.0f, e2v);
          int s = ms * 4 + r;
          bool gt = sim > b1[s];
          b2[s] = fmaxf(b2[s], gt ? b1[s] : sim);
          if (gt) { b1[s] = sim; i1[s] = c; }
        }
    }
  }

  // cross-lane reduce over the 16 col-lanes (masks 1,2,4,8), idx tie-break min
  #pragma unroll
  for (int mask = 1; mask <= 8; mask <<= 1) {
    #pragma unroll
    for (int s = 0; s < 8; ++s) {
      float ov1 = __shfl_xor(b1[s], mask);
      int   oi  = __shfl_xor(i1[s], mask);
      float ov2 = __shfl_xor(b2[s], mask);
      float nb2 = fmaxf(fmaxf(b2[s], ov2), fminf(b1[s], ov1));
      bool take = (ov1 > b1[s]) || (ov1 == b1[s] && oi < i1[s]);
      if (take) { b1[s] = ov1; i1[s] = oi; }
      b2[s] = nb2;
    }
  }

  __syncthreads();   // done with GEMM tiles; reuse LDS
  float* rv1 = (float*)&tiles[0][0];
  int*   ri1 = (int*)&tiles[1][0];
  float* rv2 = (float*)&tiles[2][0];
  if (wc == 0 && lr == 0) {
    #pragma unroll
    for (int s = 0; s < 8; ++s) {
      int R = wr * 32 + (s >> 2) * 16 + q * 4 + (s & 3);
      rv1[R] = b1[s]; ri1[R] = i1[s]; rv2[R] = b2[s];
    }
  }
  __syncthreads();
  if (wc == 1 && lr == 0) {
    #pragma unroll
    for (int s = 0; s < 8; ++s) {
      int R = wr * 32 + (s >> 2) * 16 + q * 4 + (s & 3);
      float av1 = rv1[R]; int ai = ri1[R]; float av2 = rv2[R];
      float m2 = fmaxf(fmaxf(av2, b2[s]), fminf(av1, b1[s]));
      bool take = (b1[s] > av1) || (b1[s] == av1 && i1[s] < ai);
      float m1 = take ? b1[s] : av1;
      int   mi = take ? i1[s] : ai;
      idxs[row0 + R] = mi;
      if (m1 - m2 < MARGIN) {
        int p = atomicAdd(cnt, 1);
        worklist[p] = row0 + R;
      }
    }
  }
}

// ---------------- exact fp32 rescue, batched 8 rows per block-iteration ----------------
__global__ __launch_bounds__(256) void rescue_kernel(const float* __restrict__ z,
                                                     const float* __restrict__ emb,
                                                     const float* __restrict__ e2,
                                                     int* __restrict__ idxs,
                                                     const int* __restrict__ cnt,
                                                     const int* __restrict__ worklist) {
  __shared__ float zr[RB][EDIM];     // 8 KB
  __shared__ float z2s[RB];
  __shared__ int   rows_s[RB];
  __shared__ float rv[RB][256];      // 8 KB
  __shared__ int   ri[RB][256];      // 8 KB
  const int tid = threadIdx.x;
  const float4* z4 = (const float4*)z;
  const int n = cnt[0];

  for (int base = blockIdx.x * RB; base < n; base += gridDim.x * RB) {
    const int nr = min(RB, n - base);
    for (int i = tid; i < nr * 64; i += 256) {
      int r = i >> 6, k4 = i & 63;
      int row = worklist[base + r];
      ((float4*)zr[r])[k4] = z4[(size_t)row * 64 + k4];
    }
    if (tid < nr) rows_s[tid] = worklist[base + tid];
    __syncthreads();
    if (tid < nr) {    // per-row ||z||^2, R1-sequential rounding
      float s = 0.f;
      const float4* p = (const float4*)zr[tid];
      for (int k = 0; k < 64; ++k) {
        float4 v = p[k];
        s += v.x * v.x; s += v.y * v.y; s += v.z * v.z; s += v.w * v.w;
      }
      z2s[tid] = s;
    }
    __syncthreads();

    float bv[RB]; int bi[RB];
    #pragma unroll
    for (int r = 0; r < RB; ++r) { bv[r] = -3.4e38f; bi[r] = 0; }

    #pragma unroll
    for (int cc = 0; cc < 4; ++cc) {
      int c = cc * 256 + tid;
      const float4* e4 = (const float4*)(emb + (size_t)c * EDIM);
      float dot[RB];
      #pragma unroll
      for (int r = 0; r < RB; ++r) dot[r] = 0.f;
      for (int k4 = 0; k4 < 64; ++k4) {
        float4 b = e4[k4];
        #pragma unroll
        for (int r = 0; r < RB; ++r) {
          float4 a = ((const float4*)zr[r])[k4];   // LDS broadcast
          dot[r] = fmaf(a.x, b.x, dot[r]);
          dot[r] = fmaf(a.y, b.y, dot[r]);
          dot[r] = fmaf(a.z, b.z, dot[r]);
          dot[r] = fmaf(a.w, b.w, dot[r]);
        }
      }
      #pragma unroll
      for (int r = 0; r < RB; ++r) {
        float t = z2s[r] + e2[c];
        float s = fmaf(dot[r], -2.0f, t);
        if (s > bv[r] || (s == bv[r] && c < bi[r])) { bv[r] = s; bi[r] = c; }
      }
    }

    #pragma unroll
    for (int r = 0; r < RB; ++r) { rv[r][tid] = bv[r]; ri[r][tid] = bi[r]; }
    __syncthreads();
    for (int sN = 128; sN > 0; sN >>= 1) {
      if (tid < sN) {
        #pragma unroll
        for (int r = 0; r < RB; ++r) {
          float ov = rv[r][tid + sN]; int oi = ri[r][tid + sN];
          if (ov > rv[r][tid] || (ov == rv[r][tid] && oi < ri[r][tid])) {
            rv[r][tid] = ov; ri[r][tid] = oi;
          }
        }
      }
      __syncthreads();
    }
    if (tid < nr) idxs[rows_s[tid]] = ri[tid][0];
    __syncthreads();
  }
}

// ---------------- gather z_q + squared-diff partial sums + idxf ----------------
__global__ __launch_bounds__(256) void gather_kernel(
    const float* __restrict__ z, const float* __restrict__ emb,
    const int* __restrict__ idxs, float* __restrict__ out,
    float* __restrict__ partials, float* __restrict__ idxf) {
  const int tid = threadIdx.x;
  const int b = blockIdx.x;            // 1024 blocks, 64 rows each
  const float4* z4 = (const float4*)z;
  float4* q4 = (float4*)out;

  if (tid < 64) {
    int r2 = b * 64 + tid;
    idxf[r2] = (float)idxs[r2];
  }

  float acc = 0.f;
  #pragma unroll
  for (int i = 0; i < 16; ++i) {
    int f = b * 4096 + tid + 256 * i;  // float4 index
    int row = f >> 6;
    int c4 = f & 63;
    int e = idxs[row];
    float4 ev = *(const float4*)&emb[(size_t)e * EDIM + 4 * c4];
    float4 zv = z4[f];
    q4[f] = ev;
    float dx = ev.x - zv.x, dy = ev.y - zv.y, dz = ev.z - zv.z, dw = ev.w - zv.w;
    acc += dx * dx + dy * dy + dz * dz + dw * dw;
  }
  __shared__ float red[256];
  red[tid] = acc;
  __syncthreads();
  #pragma unroll
  for (int sN = 128; sN > 0; sN >>= 1) {
    if (tid < sN) red[tid] += red[tid + sN];
    __syncthreads();
  }
  if (tid == 0) partials[b] = red[0];
}

__global__ void finalize_kernel(const float* __restrict__ partials,
                                float* __restrict__ out) {
  if (threadIdx.x == 0 && blockIdx.x == 0) {
    double s = 0.0;
    for (int i = 0; i < 1024; ++i) s += (double)partials[i];
    float m = (float)(s / 16777216.0);
    out[OUT_VQ] = m;
    out[OUT_CM] = 0.25f * m;
  }
}

extern "C" void kernel_launch(void* const* d_in, const int* in_sizes, int n_in,
                              void* d_out, int out_size, void* d_ws, size_t ws_size,
                              hipStream_t stream) {
  const float* z   = (const float*)d_in[0];
  const float* emb = (const float*)d_in[1];
  float* out = (float*)d_out;

  // z_q region doubles as bf16 hi/lo staging (64MB = 32MB hi + 32MB lo), overwritten by gather
  unsigned short* zhi = (unsigned short*)d_out;
  unsigned short* zlo = zhi + 16777216;

  // ws: ehi 512KB | elo 512KB | e2 4KB | idxs 256KB | partials 4KB | cnt 16B | worklist 256KB
  unsigned short* ehi = (unsigned short*)d_ws;
  unsigned short* elo = ehi + 262144;
  float* e2       = (float*)(elo + 262144);
  int*   idxs     = (int*)(e2 + 1024);
  float* partials = (float*)(idxs + 65536);
  int*   cnt      = (int*)(partials + 1024);
  int*   worklist = cnt + 4;

  zsplit_kernel<<<8192, 256, 0, stream>>>(z, zhi, zlo);
  esplit_kernel<<<128, 256, 0, stream>>>(emb, ehi, elo);
  e2_kernel<<<NEMB / 256, 256, 0, stream>>>(emb, e2, cnt);
  argmax_kernel<<<ROWS / 128, 512, 0, stream>>>(zhi, zlo, ehi, elo, e2, idxs, cnt, worklist);
  rescue_kernel<<<1024, 256, 0, stream>>>(z, emb, e2, idxs, cnt, worklist);
  gather_kernel<<<1024, 256, 0, stream>>>(z, emb, idxs, out, partials, out + OUT_IDX);
  finalize_kernel<<<1, 64, 0, stream>>>(partials, out);
}